// Round 14
// baseline (1577.903 us; speedup 1.0000x reference)
//
#include <hip/hip_runtime.h>
#include <math.h>

// ---------------- types ----------------
typedef unsigned short u16;
typedef __bf16 bf16x8 __attribute__((ext_vector_type(8)));
typedef float  f32x4  __attribute__((ext_vector_type(4)));
typedef unsigned short u16x8 __attribute__((ext_vector_type(8)));
typedef unsigned short u16x4 __attribute__((ext_vector_type(4)));

union B8 { u16x8 u; bf16x8 b; };

__device__ __forceinline__ u16 f2bf(float x) {
  unsigned int u = __float_as_uint(x);
  unsigned int r = (u + 0x7fffu + ((u >> 16) & 1u)) >> 16;
  return (u16)r;
}
__device__ __forceinline__ float bf2f(u16 h) {
  return __uint_as_float(((unsigned int)h) << 16);
}

// async global->LDS, 16B per lane. lds ptr must be wave-uniform (HW adds lane*16).
__device__ __forceinline__ void gload16(const void* g, void* l) {
  __builtin_amdgcn_global_load_lds(
      (const __attribute__((address_space(1))) unsigned int*)g,
      (__attribute__((address_space(3))) unsigned int*)l, 16, 0, 0);
}

// ---------------- elementwise cast f32 -> bf16 ----------------
__global__ __launch_bounds__(256) void cast_kernel(const float* __restrict__ in,
                                                   u16* __restrict__ out, int n4) {
  int i = blockIdx.x * 256 + threadIdx.x;
  if (i >= n4) return;
  f32x4 v = *(const f32x4*)(in + (size_t)i * 4);
  u16x4 o;
  o[0] = f2bf(v[0]); o[1] = f2bf(v[1]); o[2] = f2bf(v[2]); o[3] = f2bf(v[3]);
  *(u16x4*)(out + (size_t)i * 4) = o;
}

// ---------------- transpose + cast: in [z][R][C] f32 -> out [z][C][R] bf16 ----------------
__global__ void transpose_cast_kernel(const float* __restrict__ in, u16* __restrict__ out,
                                      int R, int C) {
  __shared__ float tile[32][33];
  int z = blockIdx.z;
  int r0 = blockIdx.y * 32, c0 = blockIdx.x * 32;
  const float* ip = in + (size_t)z * R * C;
  u16* op = out + (size_t)z * R * C;
  int tx = threadIdx.x, ty = threadIdx.y;  // 32 x 8
  #pragma unroll
  for (int i = 0; i < 32; i += 8)
    tile[ty + i][tx] = ip[(size_t)(r0 + ty + i) * C + c0 + tx];
  __syncthreads();
  #pragma unroll
  for (int i = 0; i < 32; i += 8)
    op[(size_t)(c0 + ty + i) * R + r0 + tx] = f2bf(tile[tx][ty + i]);
}

// ---------------- LayerNorm (f32 in, bf16 out) ----------------
__global__ __launch_bounds__(256) void ln_kernel(const float* __restrict__ in,
                                                 const float* __restrict__ g,
                                                 const float* __restrict__ bt,
                                                 u16* __restrict__ out) {
  __shared__ float red[4];
  int row = blockIdx.x;
  int t = threadIdx.x;
  int lane = t & 63, wid = t >> 6;
  f32x4 x = *(const f32x4*)(in + (size_t)row * 1024 + t * 4);
  float s = x[0] + x[1] + x[2] + x[3];
  #pragma unroll
  for (int o = 32; o > 0; o >>= 1) s += __shfl_down(s, o, 64);
  if (lane == 0) red[wid] = s;
  __syncthreads();
  float mean = (red[0] + red[1] + red[2] + red[3]) * (1.0f / 1024.0f);
  __syncthreads();
  float d0 = x[0] - mean, d1 = x[1] - mean, d2 = x[2] - mean, d3 = x[3] - mean;
  float s2 = d0 * d0 + d1 * d1 + d2 * d2 + d3 * d3;
  #pragma unroll
  for (int o = 32; o > 0; o >>= 1) s2 += __shfl_down(s2, o, 64);
  if (lane == 0) red[wid] = s2;
  __syncthreads();
  float var = (red[0] + red[1] + red[2] + red[3]) * (1.0f / 1024.0f);
  float rstd = rsqrtf(var + 1e-5f);
  f32x4 gg = *(const f32x4*)(g + t * 4);
  f32x4 bb = *(const f32x4*)(bt + t * 4);
  u16x4 o;
  o[0] = f2bf(d0 * rstd * gg[0] + bb[0]);
  o[1] = f2bf(d1 * rstd * gg[1] + bb[1]);
  o[2] = f2bf(d2 * rstd * gg[2] + bb[2]);
  o[3] = f2bf(d3 * rstd * gg[3] + bb[3]);
  *(u16x4*)(out + (size_t)row * 1024 + t * 4) = o;
}

// fast GELU (tanh form): |err| vs erf-GELU <= ~1e-3 abs
__device__ __forceinline__ float gelu_f(float x) {
  float y = 0.79788456080286536f * (x + 0.044715f * x * x * x);
  return x - __fdividef(x, __expf(2.0f * y) + 1.0f);
}

// swizzle (BK=32 tiles, 4 granules of 16B per 64B row): slot = colg ^ (row bits 1..2)
// verified conflict-free (R6: SQ_LDS_BANK_CONFLICT = 0); both-sides consistent.
#define SRC_COL(t) ((((t) & 3) ^ (((t) >> 3) & 3)) * 8)

// ---------------- 128x128 GEMM: 4 waves, 2 bufs (32KB LDS), 5 blocks/CU ----------
// R13 diagnosis: MfmaUtil 23 + VALU 13 + HBM 22%-of-achiev -> latency-bound, both pipes
// idle ~60%. Fix = TLP: 2 bufs -> 32KB -> 5 blocks/CU (20 waves), m97-style per-iter
// vmcnt(0)+single-barrier, distance-1 prefetch. Cross-block interleave hides the drains.
// CHUNK: 0 = 1D m-row chunks; 2 = 2D 4m x 2n A-resident regions (w1).
// ZB=0: z = split-K chunk (bias/res on z==0). ZB=1: z = expert batch.
// MODE 0: bf16 = acc + bias (coalesced) | 1: f32 atomicAdd(acc+[z0](bias+res))
// MODE 2: bf16 = GELU(acc + bias)       | 3: f32 atomicAdd(prob*(acc+bias))
template <int MODE, int ZB, int CHUNK>
__global__ __launch_bounds__(256, 5) void gemm_bt(const u16* __restrict__ A,
                                                  const u16* __restrict__ B,
                                                  const float* __restrict__ bias,
                                                  const float* __restrict__ extra,
                                                  void* __restrict__ out,
                                                  int M, int N, int K, int expertBase,
                                                  int kChunk, size_t saz, size_t sbz,
                                                  int sbiasz, size_t soutz) {
  __shared__ u16 sm[16384];  // 2 bufs x (A[128][32] + B[128][32]) = 32KB
  const int tid = threadIdx.x;
  const int lane = tid & 63;
  const int wid = tid >> 6;
  const int wr = wid >> 1, wc = wid & 1;  // 2x2 waves, 64x64 each
  const int l15 = lane & 15;
  const int kg = lane >> 4;
  const int kgr8 = (kg ^ ((lane >> 1) & 3)) * 8;
  const int z = blockIdx.z;

  if (ZB) { A += (size_t)z * saz; B += (size_t)z * sbz; bias += z * sbiasz; }
  const int kOff = ZB ? 0 : z * kChunk;
  const bool z0 = ZB ? true : (z == 0);
  const int expert = expertBase + (ZB ? z : 0);

  const int gx = gridDim.x, gy = gridDim.y;
  const int bid = blockIdx.y * gx + blockIdx.x;
  const int xcd = bid & 7;
  const int idx = bid >> 3;
  int m0, n0;
  if constexpr (CHUNK == 0) {
    const int nwg = gx * gy;
    const int swz = xcd * (nwg >> 3) + idx;
    m0 = (swz / gx) * 128;
    n0 = (swz % gx) * 128;
  } else {
    const int hy = gy >> 2, hx = gx >> 1;
    const int cy = xcd >> 1, cx = xcd & 1;
    m0 = (cy * hy + idx % hy) * 128;   // m fastest: A region L2-resident
    n0 = (cx * hx + idx / hy) * 128;
  }

  f32x4 acc[4][4];
  #pragma unroll
  for (int i = 0; i < 4; i++)
    #pragma unroll
    for (int j = 0; j < 4; j++) acc[i][j] = f32x4{0.f, 0.f, 0.f, 0.f};

  const int sc = SRC_COL(tid);
  const u16* ga = A + (size_t)(m0 + (tid >> 2)) * K + sc + kOff;
  const u16* gb = B + (size_t)(n0 + (tid >> 2)) * K + sc + kOff;
  const size_t rowskip = (size_t)64 * K;

#define STG(b, kt)                                                  \
  do {                                                              \
    u16* d = sm + (b) * 8192 + wid * 512;                           \
    gload16(ga + (kt), d);                                          \
    gload16(ga + rowskip + (kt), d + 2048);                         \
    gload16(gb + (kt), d + 4096);                                   \
    gload16(gb + rowskip + (kt), d + 6144);                         \
  } while (0)

  const int NT = kChunk >> 5;
  STG(0, 0);
  for (int t = 0; t < NT; ++t) {
    // tile t's loads were issued one iteration ago by THIS wave; drain own loads,
    // then barrier makes every wave's LDS writes visible (m97 pattern, 5-block TLP
    // absorbs the drain).
    asm volatile("s_waitcnt vmcnt(0)" ::: "memory");
    __builtin_amdgcn_s_barrier();
    if (t + 1 < NT) STG((t + 1) & 1, (t + 1) * 32);
    __builtin_amdgcn_sched_barrier(0);
    __builtin_amdgcn_s_setprio(1);
    const u16* base = sm + (t & 1) * 8192;
    B8 af[4], bfr[4];
    #pragma unroll
    for (int i = 0; i < 4; i++) {
      af[i].u  = *(const u16x8*)(base + (wr * 64 + l15 + i * 16) * 32 + kgr8);
      bfr[i].u = *(const u16x8*)(base + 4096 + (wc * 64 + l15 + i * 16) * 32 + kgr8);
    }
    #pragma unroll
    for (int i = 0; i < 4; i++)
      #pragma unroll
      for (int j = 0; j < 4; j++)
        acc[i][j] = __builtin_amdgcn_mfma_f32_16x16x32_bf16(af[i].b, bfr[j].b, acc[i][j], 0, 0, 0);
    __builtin_amdgcn_s_setprio(0);
  }
#undef STG

  const int orow0 = m0 + wr * 64 + (lane >> 4) * 4;
  const int ocol0 = n0 + wc * 64 + l15;

  if constexpr (MODE == 0 || MODE == 2) {
    u16* outp = (u16*)out + (ZB ? (size_t)z * soutz : 0);
    __builtin_amdgcn_s_barrier();  // all sm reads done
    u16* rp = sm + wid * 1152;     // [16][72]
    const int mrow0 = m0 + wr * 64;
    const int cbase = n0 + wc * 64;
    #pragma unroll
    for (int i = 0; i < 4; i++) {
      #pragma unroll
      for (int j = 0; j < 4; j++) {
        const float bb = bias[cbase + j * 16 + l15];
        #pragma unroll
        for (int p = 0; p < 4; p++) {
          float vb = acc[i][j][p] + bb;
          if constexpr (MODE == 2) vb = gelu_f(vb);
          rp[((lane >> 4) * 4 + p) * 72 + j * 16 + l15] = f2bf(vb);
        }
      }
      asm volatile("s_waitcnt lgkmcnt(0)" ::: "memory");
      #pragma unroll
      for (int rr = 0; rr < 4; rr++) {
        const int r16 = rr * 4 + (lane >> 4);
        u16x4 v4 = *(const u16x4*)&rp[r16 * 72 + l15 * 4];
        *(u16x4*)(outp + (size_t)(mrow0 + i * 16 + r16) * N + cbase + l15 * 4) = v4;
      }
      asm volatile("s_waitcnt lgkmcnt(0)" ::: "memory");
    }
  } else {
    float* outp = (float*)out + (ZB ? (size_t)z * soutz : 0);
    #pragma unroll
    for (int i = 0; i < 4; i++) {
      float pr_[4];
      if constexpr (MODE == 3) {
        #pragma unroll
        for (int p = 0; p < 4; p++)
          pr_[p] = extra[(size_t)(orow0 + i * 16 + p) * 8 + expert];
      }
      #pragma unroll
      for (int j = 0; j < 4; j++) {
        const int gcol = ocol0 + j * 16;
        const float bb = bias[gcol];
        #pragma unroll
        for (int p = 0; p < 4; p++) {
          const int grow = orow0 + i * 16 + p;
          const size_t off = (size_t)grow * N + gcol;
          if constexpr (MODE == 1) {
            atomicAdd(&outp[off], acc[i][j][p] + (z0 ? bb + extra[off] : 0.f));
          } else {
            atomicAdd(&outp[off], pr_[p] * (acc[i][j][p] + bb));
          }
        }
      }
    }
  }
}

// ---------------- MFMA flash attention: block=(b,head), 4 waves x 64 q-rows ----------------
__global__ __launch_bounds__(256) void attn_mfma(const u16* __restrict__ qb, int qs,
                                                 const u16* __restrict__ kb_, int ks,
                                                 const u16* __restrict__ vb, int vs,
                                                 u16* __restrict__ outp) {
  __shared__ u16 Ks[64][72];
  __shared__ u16 Vt[64][72];
  __shared__ u16 Pl[4][64][72];
  const int t = threadIdx.x;
  const int lane = t & 63;
  const int w = t >> 6;
  const int b = blockIdx.x >> 4;
  const int h = blockIdx.x & 15;
  const int lr = lane & 15;
  const int kg = lane >> 4;
  const size_t qrow0 = (size_t)b * 256 + w * 64;

  B8 qf[4][2];
  #pragma unroll
  for (int i = 0; i < 4; i++)
    #pragma unroll
    for (int kk = 0; kk < 2; kk++)
      qf[i][kk].u = *(const u16x8*)(qb + (qrow0 + i * 16 + lr) * qs + h * 64 + kk * 32 + kg * 8);

  f32x4 ao[4][4];
  float m_[4][4], l_[4][4];
  #pragma unroll
  for (int i = 0; i < 4; i++)
    #pragma unroll
    for (int n = 0; n < 4; n++) ao[i][n] = f32x4{0.f, 0.f, 0.f, 0.f};
  #pragma unroll
  for (int i = 0; i < 4; i++)
    #pragma unroll
    for (int p = 0; p < 4; p++) { m_[i][p] = -1e30f; l_[i][p] = 0.f; }

  for (int jt = 0; jt < 4; ++jt) {
    __syncthreads();
    {
      int r = t >> 2, c = (t & 3) * 16;
      const u16* src = kb_ + ((size_t)b * 256 + jt * 64 + r) * ks + h * 64 + c;
      *(u16x8*)&Ks[r][c] = *(const u16x8*)src;
      *(u16x8*)&Ks[r][c + 8] = *(const u16x8*)(src + 8);
      int jj = t & 63;
      const u16* vsrc = vb + ((size_t)b * 256 + jt * 64 + jj) * vs + h * 64 + w * 16;
      u16x8 v0 = *(const u16x8*)vsrc;
      u16x8 v1 = *(const u16x8*)(vsrc + 8);
      #pragma unroll
      for (int d = 0; d < 8; d++) Vt[w * 16 + d][jj] = v0[d];
      #pragma unroll
      for (int d = 0; d < 8; d++) Vt[w * 16 + 8 + d][jj] = v1[d];
    }
    __syncthreads();

    B8 kf[2][4];
    #pragma unroll
    for (int kk = 0; kk < 2; kk++)
      #pragma unroll
      for (int n = 0; n < 4; n++)
        kf[kk][n].u = *(const u16x8*)&Ks[n * 16 + lr][kk * 32 + kg * 8];

    #pragma unroll
    for (int i = 0; i < 4; i++) {
      f32x4 s[4];
      #pragma unroll
      for (int n = 0; n < 4; n++) s[n] = f32x4{0.f, 0.f, 0.f, 0.f};
      #pragma unroll
      for (int kk = 0; kk < 2; kk++)
        #pragma unroll
        for (int n = 0; n < 4; n++)
          s[n] = __builtin_amdgcn_mfma_f32_16x16x32_bf16(qf[i][kk].b, kf[kk][n].b, s[n], 0, 0, 0);
      #pragma unroll
      for (int p = 0; p < 4; p++) {
        float pm = fmaxf(fmaxf(s[0][p], s[1][p]), fmaxf(s[2][p], s[3][p])) * 0.125f;
        #pragma unroll
        for (int mk = 1; mk < 16; mk <<= 1) pm = fmaxf(pm, __shfl_xor(pm, mk, 16));
        float mn = fmaxf(m_[i][p], pm);
        float scl = __expf(m_[i][p] - mn);
        m_[i][p] = mn;
        float rs = 0.f;
        #pragma unroll
        for (int n = 0; n < 4; n++) {
          float e = __expf(s[n][p] * 0.125f - mn);
          Pl[w][i * 16 + kg * 4 + p][n * 16 + lr] = f2bf(e);
          rs += e;
        }
        #pragma unroll
        for (int mk = 1; mk < 16; mk <<= 1) rs += __shfl_xor(rs, mk, 16);
        l_[i][p] = l_[i][p] * scl + rs;
        #pragma unroll
        for (int n2 = 0; n2 < 4; n2++) ao[i][n2][p] *= scl;
      }
    }

    B8 vf[2][4];
    #pragma unroll
    for (int kk = 0; kk < 2; kk++)
      #pragma unroll
      for (int n2 = 0; n2 < 4; n2++)
        vf[kk][n2].u = *(const u16x8*)&Vt[n2 * 16 + lr][kk * 32 + kg * 8];
    #pragma unroll
    for (int i = 0; i < 4; i++) {
      #pragma unroll
      for (int kk = 0; kk < 2; kk++) {
        B8 pa;
        pa.u = *(const u16x8*)&Pl[w][i * 16 + lr][kk * 32 + kg * 8];
        #pragma unroll
        for (int n2 = 0; n2 < 4; n2++)
          ao[i][n2] = __builtin_amdgcn_mfma_f32_16x16x32_bf16(pa.b, vf[kk][n2].b, ao[i][n2], 0, 0, 0);
      }
    }
  }

  #pragma unroll
  for (int i = 0; i < 4; i++) {
    #pragma unroll
    for (int p = 0; p < 4; p++) {
      const float inv = 1.0f / l_[i][p];
      const size_t row = qrow0 + i * 16 + kg * 4 + p;
      #pragma unroll
      for (int n2 = 0; n2 < 4; n2++)
        outp[row * 1024 + h * 64 + n2 * 16 + lr] = f2bf(ao[i][n2][p] * inv);
    }
  }
}

// ---------------- mean over T (coalesced) ----------------
__global__ __launch_bounds__(256) void mean2_kernel(const float* __restrict__ in,
                                                    float* __restrict__ out) {
  __shared__ float part[128];
  const int blk = blockIdx.x;
  const int b = blk >> 3, ch = blk & 7;
  const int t = threadIdx.x;
  const int col = ch * 128 + (t & 127);
  const int half = t >> 7;
  const float* p = in + (size_t)b * 262144 + (size_t)half * 131072 + col;
  float s = 0.f;
  for (int r = 0; r < 128; r++) s += p[(size_t)r * 1024];
  if (half) part[t & 127] = s;
  __syncthreads();
  if (!half) out[b * 1024 + col] = (s + part[t & 127]) * (1.0f / 256.0f);
}

// ---------------- router gate ----------------
__global__ __launch_bounds__(256) void gate_kernel(const float* __restrict__ x,
                                                   const float* __restrict__ ctx,
                                                   const float* __restrict__ gw,
                                                   const float* __restrict__ gb,
                                                   float* __restrict__ probs, int rowoff) {
  __shared__ float lg[8];
  const int tok = blockIdx.x;
  const int b = tok >> 8;
  const int t = threadIdx.x;
  const int e = t >> 5, sl = t & 31;
  const float* xr = x + (size_t)tok * 1024;
  const float* cr = ctx + (size_t)b * 1024;
  const float* wrow = gw + (size_t)e * 2048;
  float s = 0.f;
  for (int c = sl; c < 1024; c += 32) s += xr[c] * wrow[c] + cr[c] * wrow[1024 + c];
  #pragma unroll
  for (int o = 16; o > 0; o >>= 1) s += __shfl_down(s, o, 32);
  if (sl == 0) lg[e] = s + gb[e];
  __syncthreads();
  if (t == 0) {
    float mx = lg[0];
    #pragma unroll
    for (int i = 1; i < 8; i++) mx = fmaxf(mx, lg[i]);
    float ex[8], sum = 0.f;
    #pragma unroll
    for (int i = 0; i < 8; i++) { ex[i] = expf(lg[i] - mx); sum += ex[i]; }
    float inv = 1.0f / sum;
    #pragma unroll
    for (int i = 0; i < 8; i++) probs[(size_t)(rowoff + tok) * 8 + i] = ex[i] * inv;
  }
}

// ---------------- final: out = residual + moe_acc ----------------
__global__ __launch_bounds__(256) void final_add_kernel(const float* __restrict__ q3,
                                                        const float* __restrict__ img,
                                                        const float* __restrict__ moe,
                                                        float* __restrict__ out) {
  size_t i = (size_t)blockIdx.x * 256 + threadIdx.x;
  f32x4 m4 = *(const f32x4*)(moe + i * 4);
  f32x4 a4 = (i < 524288) ? *(const f32x4*)(q3 + i * 4)
                          : *(const f32x4*)(img + (i - 524288) * 4);
  f32x4 r;
  r[0] = a4[0] + m4[0]; r[1] = a4[1] + m4[1]; r[2] = a4[2] + m4[2]; r[3] = a4[3] + m4[3];
  *(f32x4*)(out + i * 4) = r;
}

// ================= launch =================
extern "C" void kernel_launch(void* const* d_in, const int* in_sizes, int n_in,
                              void* d_out, int out_size, void* d_ws, size_t ws_size,
                              hipStream_t stream) {
  const float* query_in = (const float*)d_in[0];
  const float* image_in = (const float*)d_in[1];
  const float* text_in  = (const float*)d_in[2];
  const float* sa_in_w  = (const float*)d_in[3];
  const float* sa_in_b  = (const float*)d_in[4];
  const float* sa_out_w = (const float*)d_in[5];
  const float* sa_out_b = (const float*)d_in[6];
  const float* ca_in_w  = (const float*)d_in[7];
  const float* ca_in_b  = (const float*)d_in[8];
  const float* ca_out_w = (const float*)d_in[9];
  const float* ca_out_b = (const float*)d_in[10];
  const float* img_gate_w = (const float*)d_in[11];
  const float* img_gate_b = (const float*)d_in[12];
  const float* txt_gate_w = (const float*)d_in[13];
  const float* txt_gate_b = (const float*)d_in[14];
  const float* lnq_g = (const float*)d_in[15];
  const float* lnq_b = (const float*)d_in[16];
  const float* lnc_g = (const float*)d_in[17];
  const float* lnc_b = (const float*)d_in[18];
  const float* lnf_g = (const float*)d_in[19];
  const float* lnf_b = (const float*)d_in[20];
  const float* ew1 = (const float*)d_in[21];
  const float* eb1 = (const float*)d_in[22];
  const float* ew2 = (const float*)d_in[23];
  const float* eb2 = (const float*)d_in[24];

  char* base = (char*)d_ws;
  size_t off = 0;
  auto alloc = [&](size_t bytes) -> char* {
    char* p = base + off;
    off += (bytes + 255) & ~(size_t)255;
    return p;
  };

  u16* wsa_in  = (u16*)alloc((size_t)3072 * 1024 * 2);
  u16* wsa_out = (u16*)alloc((size_t)1024 * 1024 * 2);
  u16* wca_in  = (u16*)alloc((size_t)3072 * 1024 * 2);
  u16* wca_out = (u16*)alloc((size_t)1024 * 1024 * 2);
  u16* w1T = (u16*)alloc((size_t)8 * 4096 * 1024 * 2);  // [E][F][H] bf16
  u16* w2T = (u16*)alloc((size_t)8 * 4096 * 1024 * 2);  // [E][H][F] bf16
  char* big = alloc((size_t)67108864);                  // 64MB: attn overlays, then h1 pair
  float* q3 = (float*)alloc((size_t)2048 * 1024 * 4);
  u16* xmoe = (u16*)alloc((size_t)4096 * 1024 * 2);
  float* moeac = (float*)alloc((size_t)4096 * 1024 * 4);
  float* probs = (float*)alloc((size_t)4096 * 8 * 4);
  float* ctx = (float*)alloc((size_t)2 * 8192 * 4);

  // big-region overlays (liveness-disjoint: attention phase, then MoE h1 pair)
  u16* qn      = (u16*)big;
  u16* qkv     = (u16*)(big + 4194304);                // [2048][3072]
  u16* attn_o  = (u16*)(big + 16777216);               // [2048][1024]
  float* q2    = (float*)(big + 20971520);             // [2048][1024] f32
  u16* cnorm   = (u16*)(big + 29360128);               // [2048][1024]
  u16* qca     = (u16*)(big + 33554432);               // [2048][1024]
  u16* kvca    = (u16*)(big + 37748736);               // [2048][2048]
  u16* h1p     = (u16*)big;                            // [2][4096][4096] bf16 = 64MB
  u16* img_bf  = xmoe + (size_t)2048 * 1024;           // image bf16 = MoE rows 2048+

  // ---- weight prep ----
  cast_kernel<<<3072, 256, 0, stream>>>(sa_in_w, wsa_in, 786432);
  cast_kernel<<<1024, 256, 0, stream>>>(sa_out_w, wsa_out, 262144);
  cast_kernel<<<3072, 256, 0, stream>>>(ca_in_w, wca_in, 786432);
  cast_kernel<<<1024, 256, 0, stream>>>(ca_out_w, wca_out, 262144);
  transpose_cast_kernel<<<dim3(128, 32, 8), dim3(32, 8), 0, stream>>>(ew1, w1T, 1024, 4096);
  transpose_cast_kernel<<<dim3(32, 128, 8), dim3(32, 8), 0, stream>>>(ew2, w2T, 4096, 1024);
  cast_kernel<<<2048, 256, 0, stream>>>(image_in, img_bf, 524288);

  // ---- self-attention ----
  ln_kernel<<<2048, 256, 0, stream>>>(query_in, lnq_g, lnq_b, qn);
  gemm_bt<0, 0, 0><<<dim3(24, 16), 256, 0, stream>>>(qn, wsa_in, sa_in_b, nullptr, qkv,
                                                     2048, 3072, 1024, 0, 1024, 0, 0, 0, 0);
  attn_mfma<<<128, 256, 0, stream>>>(qkv, 3072, qkv + 1024, 3072, qkv + 2048, 3072, attn_o);
  hipMemsetAsync(q2, 0, (size_t)2048 * 1024 * 4, stream);
  gemm_bt<1, 0, 0><<<dim3(8, 16, 2), 256, 0, stream>>>(attn_o, wsa_out, sa_out_b, query_in, q2,
                                                       2048, 1024, 1024, 0, 512, 0, 0, 0, 0);

  // ---- cross-attention ----
  ln_kernel<<<2048, 256, 0, stream>>>(q2, lnc_g, lnc_b, cnorm);
  gemm_bt<0, 0, 0><<<dim3(8, 16), 256, 0, stream>>>(cnorm, wca_in, ca_in_b, nullptr, qca,
                                                    2048, 1024, 1024, 0, 1024, 0, 0, 0, 0);
  gemm_bt<0, 0, 0><<<dim3(16, 16), 256, 0, stream>>>(img_bf, wca_in + (size_t)1024 * 1024,
                                                     ca_in_b + 1024, nullptr, kvca,
                                                     2048, 2048, 1024, 0, 1024, 0, 0, 0, 0);
  attn_mfma<<<128, 256, 0, stream>>>(qca, 1024, kvca, 2048, kvca + 1024, 2048, attn_o);
  hipMemsetAsync(q3, 0, (size_t)2048 * 1024 * 4, stream);
  gemm_bt<1, 0, 0><<<dim3(8, 16, 2), 256, 0, stream>>>(attn_o, wca_out, ca_out_b, q2, q3,
                                                       2048, 1024, 1024, 0, 512, 0, 0, 0, 0);

  // ---- gating ----
  mean2_kernel<<<64, 256, 0, stream>>>(image_in, ctx);
  mean2_kernel<<<64, 256, 0, stream>>>(text_in, ctx + 8192);
  gate_kernel<<<2048, 256, 0, stream>>>(q3, ctx, txt_gate_w, txt_gate_b, probs, 0);
  gate_kernel<<<2048, 256, 0, stream>>>(image_in, ctx + 8192, img_gate_w, img_gate_b, probs, 2048);

  // ---- MoE (rows 0..2047 = LN(q3), 2048..4095 = image bf16), expert pairs via z ----
  ln_kernel<<<2048, 256, 0, stream>>>(q3, lnf_g, lnf_b, xmoe);
  hipMemsetAsync(moeac, 0, (size_t)4096 * 1024 * 4, stream);
  for (int e0 = 0; e0 < 8; e0 += 2) {
    // w1: 2D A-resident XCD regions (R10-verified: FETCH 190->65MB)
    gemm_bt<2, 1, 2><<<dim3(32, 32, 2), 256, 0, stream>>>(
        xmoe, w1T + (size_t)e0 * 4194304, eb1 + (size_t)e0 * 4096, nullptr, h1p,
        4096, 4096, 1024, e0, 1024,
        /*saz*/ 0, /*sbz*/ 4194304, /*sbiasz*/ 4096, /*soutz*/ 16777216);
    // w2: 1D chunking, no split-K (P10 best)
    gemm_bt<3, 1, 0><<<dim3(8, 32, 2), 256, 0, stream>>>(
        h1p, w2T + (size_t)e0 * 4194304, eb2 + (size_t)e0 * 1024, probs, moeac,
        4096, 1024, 4096, e0, 4096,
        /*saz*/ 16777216, /*sbz*/ 4194304, /*sbiasz*/ 1024, /*soutz*/ 0);
  }

  // ---- final residual adds -> d_out ----
  final_add_kernel<<<4096, 256, 0, stream>>>(q3, image_in, moeac, (float*)d_out);
}

// Round 15
// 1130.923 us; speedup vs baseline: 1.3952x; 1.3952x over previous
//
#include <hip/hip_runtime.h>
#include <math.h>

// ---------------- types ----------------
typedef unsigned short u16;
typedef __bf16 bf16x8 __attribute__((ext_vector_type(8)));
typedef float  f32x4  __attribute__((ext_vector_type(4)));
typedef unsigned short u16x8 __attribute__((ext_vector_type(8)));
typedef unsigned short u16x4 __attribute__((ext_vector_type(4)));

union B8 { u16x8 u; bf16x8 b; };

__device__ __forceinline__ u16 f2bf(float x) {
  unsigned int u = __float_as_uint(x);
  unsigned int r = (u + 0x7fffu + ((u >> 16) & 1u)) >> 16;
  return (u16)r;
}
__device__ __forceinline__ float bf2f(u16 h) {
  return __uint_as_float(((unsigned int)h) << 16);
}

// async global->LDS, 16B per lane. lds ptr must be wave-uniform (HW adds lane*16).
__device__ __forceinline__ void gload16(const void* g, void* l) {
  __builtin_amdgcn_global_load_lds(
      (const __attribute__((address_space(1))) unsigned int*)g,
      (__attribute__((address_space(3))) unsigned int*)l, 16, 0, 0);
}

// ---------------- elementwise cast f32 -> bf16 ----------------
__global__ __launch_bounds__(256) void cast_kernel(const float* __restrict__ in,
                                                   u16* __restrict__ out, int n4) {
  int i = blockIdx.x * 256 + threadIdx.x;
  if (i >= n4) return;
  f32x4 v = *(const f32x4*)(in + (size_t)i * 4);
  u16x4 o;
  o[0] = f2bf(v[0]); o[1] = f2bf(v[1]); o[2] = f2bf(v[2]); o[3] = f2bf(v[3]);
  *(u16x4*)(out + (size_t)i * 4) = o;
}

// ---------------- transpose + cast: in [z][R][C] f32 -> out [z][C][R] bf16 ----------------
__global__ void transpose_cast_kernel(const float* __restrict__ in, u16* __restrict__ out,
                                      int R, int C) {
  __shared__ float tile[32][33];
  int z = blockIdx.z;
  int r0 = blockIdx.y * 32, c0 = blockIdx.x * 32;
  const float* ip = in + (size_t)z * R * C;
  u16* op = out + (size_t)z * R * C;
  int tx = threadIdx.x, ty = threadIdx.y;  // 32 x 8
  #pragma unroll
  for (int i = 0; i < 32; i += 8)
    tile[ty + i][tx] = ip[(size_t)(r0 + ty + i) * C + c0 + tx];
  __syncthreads();
  #pragma unroll
  for (int i = 0; i < 32; i += 8)
    op[(size_t)(c0 + ty + i) * R + r0 + tx] = f2bf(tile[tx][ty + i]);
}

// ---------------- LayerNorm (f32 in, bf16 out) ----------------
__global__ __launch_bounds__(256) void ln_kernel(const float* __restrict__ in,
                                                 const float* __restrict__ g,
                                                 const float* __restrict__ bt,
                                                 u16* __restrict__ out) {
  __shared__ float red[4];
  int row = blockIdx.x;
  int t = threadIdx.x;
  int lane = t & 63, wid = t >> 6;
  f32x4 x = *(const f32x4*)(in + (size_t)row * 1024 + t * 4);
  float s = x[0] + x[1] + x[2] + x[3];
  #pragma unroll
  for (int o = 32; o > 0; o >>= 1) s += __shfl_down(s, o, 64);
  if (lane == 0) red[wid] = s;
  __syncthreads();
  float mean = (red[0] + red[1] + red[2] + red[3]) * (1.0f / 1024.0f);
  __syncthreads();
  float d0 = x[0] - mean, d1 = x[1] - mean, d2 = x[2] - mean, d3 = x[3] - mean;
  float s2 = d0 * d0 + d1 * d1 + d2 * d2 + d3 * d3;
  #pragma unroll
  for (int o = 32; o > 0; o >>= 1) s2 += __shfl_down(s2, o, 64);
  if (lane == 0) red[wid] = s2;
  __syncthreads();
  float var = (red[0] + red[1] + red[2] + red[3]) * (1.0f / 1024.0f);
  float rstd = rsqrtf(var + 1e-5f);
  f32x4 gg = *(const f32x4*)(g + t * 4);
  f32x4 bb = *(const f32x4*)(bt + t * 4);
  u16x4 o;
  o[0] = f2bf(d0 * rstd * gg[0] + bb[0]);
  o[1] = f2bf(d1 * rstd * gg[1] + bb[1]);
  o[2] = f2bf(d2 * rstd * gg[2] + bb[2]);
  o[3] = f2bf(d3 * rstd * gg[3] + bb[3]);
  *(u16x4*)(out + (size_t)row * 1024 + t * 4) = o;
}

// fast GELU (tanh form): |err| vs erf-GELU <= ~1e-3 abs, ~3x fewer VALU ops than erff
__device__ __forceinline__ float gelu_f(float x) {
  float y = 0.79788456080286536f * (x + 0.044715f * x * x * x);
  return x - __fdividef(x, __expf(2.0f * y) + 1.0f);
}

// swizzle (BK=32 tiles, 4 granules of 16B per 64B row): slot = colg ^ (row bits 1..2)
// verified conflict-free (R6: SQ_LDS_BANK_CONFLICT = 0); both-sides consistent.
#define SRC_COL(t) ((((t) & 3) ^ (((t) >> 3) & 3)) * 8)

// ---------------- 128x128 GEMM: 4 waves, ahead-2 pipeline, 48KB LDS, 3 blocks/CU ----------
// Best-measured config (R11 bench: 1132us total). 3 bufs, counted vmcnt, A-resident chunks.
// CHUNK: 0 = 1D m-row chunks; 2 = 2D 4m x 2n A-resident regions (w1).
// ZB=0: z = split-K chunk (bias/res on z==0). ZB=1: z = expert batch.
// MODE 0: bf16 = acc + bias (coalesced) | 1: f32 atomicAdd(acc+[z0](bias+res))
// MODE 2: bf16 = GELU(acc + bias)       | 3: f32 atomicAdd(prob*(acc+bias))
template <int MODE, int ZB, int CHUNK>
__global__ __launch_bounds__(256, 3) void gemm_bt(const u16* __restrict__ A,
                                                  const u16* __restrict__ B,
                                                  const float* __restrict__ bias,
                                                  const float* __restrict__ extra,
                                                  void* __restrict__ out,
                                                  int M, int N, int K, int expertBase,
                                                  int kChunk, size_t saz, size_t sbz,
                                                  int sbiasz, size_t soutz) {
  __shared__ u16 sm[24576];  // 3 bufs x (A[128][32] + B[128][32]) = 48KB
  const int tid = threadIdx.x;
  const int lane = tid & 63;
  const int wid = tid >> 6;
  const int wr = wid >> 1, wc = wid & 1;  // 2x2 waves, 64x64 each
  const int l15 = lane & 15;
  const int kg = lane >> 4;
  const int kgr8 = (kg ^ ((lane >> 1) & 3)) * 8;
  const int z = blockIdx.z;

  if (ZB) { A += (size_t)z * saz; B += (size_t)z * sbz; bias += z * sbiasz; }
  const int kOff = ZB ? 0 : z * kChunk;
  const bool z0 = ZB ? true : (z == 0);
  const int expert = expertBase + (ZB ? z : 0);

  const int gx = gridDim.x, gy = gridDim.y;
  const int bid = blockIdx.y * gx + blockIdx.x;
  const int xcd = bid & 7;
  const int idx = bid >> 3;
  int m0, n0;
  if constexpr (CHUNK == 0) {
    const int nwg = gx * gy;
    const int swz = xcd * (nwg >> 3) + idx;
    m0 = (swz / gx) * 128;
    n0 = (swz % gx) * 128;
  } else {
    const int hy = gy >> 2, hx = gx >> 1;
    const int cy = xcd >> 1, cx = xcd & 1;
    const int mloc = idx % hy;       // m fastest: A region L2-resident
    const int nloc = idx / hy;
    m0 = (cy * hy + mloc) * 128;
    n0 = (cx * hx + nloc) * 128;
  }

  f32x4 acc[4][4];
  #pragma unroll
  for (int i = 0; i < 4; i++)
    #pragma unroll
    for (int j = 0; j < 4; j++) acc[i][j] = f32x4{0.f, 0.f, 0.f, 0.f};

  const int sc = SRC_COL(tid);
  const u16* ga = A + (size_t)(m0 + (tid >> 2)) * K + sc + kOff;
  const u16* gb = B + (size_t)(n0 + (tid >> 2)) * K + sc + kOff;
  const size_t rowskip = (size_t)64 * K;

#define STG(b, kt)                                                  \
  do {                                                              \
    u16* d = sm + (b) * 8192 + wid * 512;                           \
    gload16(ga + (kt), d);                                          \
    gload16(ga + rowskip + (kt), d + 2048);                         \
    gload16(gb + (kt), d + 4096);                                   \
    gload16(gb + rowskip + (kt), d + 6144);                         \
  } while (0)

  const int NT = kChunk >> 5;
  STG(0, 0); STG(1, 32);
  int buf = 0;
  for (int t = 0; t < NT; ++t) {
    if (t + 1 < NT) asm volatile("s_waitcnt vmcnt(4)" ::: "memory");
    else            asm volatile("s_waitcnt vmcnt(0)" ::: "memory");
    __builtin_amdgcn_s_barrier();
    if (t + 2 < NT) {
      int nb = buf + 2; if (nb >= 3) nb -= 3;
      STG(nb, (t + 2) * 32);
    }
    __builtin_amdgcn_sched_barrier(0);
    __builtin_amdgcn_s_setprio(1);
    const u16* base = sm + buf * 8192;
    B8 af[4], bfr[4];
    #pragma unroll
    for (int i = 0; i < 4; i++) {
      af[i].u  = *(const u16x8*)(base + (wr * 64 + l15 + i * 16) * 32 + kgr8);
      bfr[i].u = *(const u16x8*)(base + 4096 + (wc * 64 + l15 + i * 16) * 32 + kgr8);
    }
    #pragma unroll
    for (int i = 0; i < 4; i++)
      #pragma unroll
      for (int j = 0; j < 4; j++)
        acc[i][j] = __builtin_amdgcn_mfma_f32_16x16x32_bf16(af[i].b, bfr[j].b, acc[i][j], 0, 0, 0);
    __builtin_amdgcn_s_setprio(0);
    if (++buf >= 3) buf = 0;
  }
#undef STG

  const int orow0 = m0 + wr * 64 + (lane >> 4) * 4;
  const int ocol0 = n0 + wc * 64 + l15;

  if constexpr (MODE == 0 || MODE == 2) {
    u16* outp = (u16*)out + (ZB ? (size_t)z * soutz : 0);
    __builtin_amdgcn_s_barrier();  // all sm reads done
    u16* rp = sm + wid * 1152;     // [16][72]
    const int mrow0 = m0 + wr * 64;
    const int cbase = n0 + wc * 64;
    #pragma unroll
    for (int i = 0; i < 4; i++) {
      #pragma unroll
      for (int j = 0; j < 4; j++) {
        const float bb = bias[cbase + j * 16 + l15];
        #pragma unroll
        for (int p = 0; p < 4; p++) {
          float vb = acc[i][j][p] + bb;
          if constexpr (MODE == 2) vb = gelu_f(vb);
          rp[((lane >> 4) * 4 + p) * 72 + j * 16 + l15] = f2bf(vb);
        }
      }
      asm volatile("s_waitcnt lgkmcnt(0)" ::: "memory");
      #pragma unroll
      for (int rr = 0; rr < 4; rr++) {
        const int r16 = rr * 4 + (lane >> 4);
        u16x4 v4 = *(const u16x4*)&rp[r16 * 72 + l15 * 4];
        *(u16x4*)(outp + (size_t)(mrow0 + i * 16 + r16) * N + cbase + l15 * 4) = v4;
      }
      asm volatile("s_waitcnt lgkmcnt(0)" ::: "memory");
    }
  } else {
    float* outp = (float*)out + (ZB ? (size_t)z * soutz : 0);
    #pragma unroll
    for (int i = 0; i < 4; i++) {
      float pr_[4];
      if constexpr (MODE == 3) {
        #pragma unroll
        for (int p = 0; p < 4; p++)
          pr_[p] = extra[(size_t)(orow0 + i * 16 + p) * 8 + expert];
      }
      #pragma unroll
      for (int j = 0; j < 4; j++) {
        const int gcol = ocol0 + j * 16;
        const float bb = bias[gcol];
        #pragma unroll
        for (int p = 0; p < 4; p++) {
          const int grow = orow0 + i * 16 + p;
          const size_t off = (size_t)grow * N + gcol;
          if constexpr (MODE == 1) {
            atomicAdd(&outp[off], acc[i][j][p] + (z0 ? bb + extra[off] : 0.f));
          } else {
            atomicAdd(&outp[off], pr_[p] * (acc[i][j][p] + bb));
          }
        }
      }
    }
  }
}

// ---------------- MFMA flash attention: block=(b,head), 4 waves x 64 q-rows ----------------
__global__ __launch_bounds__(256) void attn_mfma(const u16* __restrict__ qb, int qs,
                                                 const u16* __restrict__ kb_, int ks,
                                                 const u16* __restrict__ vb, int vs,
                                                 u16* __restrict__ outp) {
  __shared__ u16 Ks[64][72];
  __shared__ u16 Vt[64][72];
  __shared__ u16 Pl[4][64][72];
  const int t = threadIdx.x;
  const int lane = t & 63;
  const int w = t >> 6;
  const int b = blockIdx.x >> 4;
  const int h = blockIdx.x & 15;
  const int lr = lane & 15;
  const int kg = lane >> 4;
  const size_t qrow0 = (size_t)b * 256 + w * 64;

  B8 qf[4][2];
  #pragma unroll
  for (int i = 0; i < 4; i++)
    #pragma unroll
    for (int kk = 0; kk < 2; kk++)
      qf[i][kk].u = *(const u16x8*)(qb + (qrow0 + i * 16 + lr) * qs + h * 64 + kk * 32 + kg * 8);

  f32x4 ao[4][4];
  float m_[4][4], l_[4][4];
  #pragma unroll
  for (int i = 0; i < 4; i++)
    #pragma unroll
    for (int n = 0; n < 4; n++) ao[i][n] = f32x4{0.f, 0.f, 0.f, 0.f};
  #pragma unroll
  for (int i = 0; i < 4; i++)
    #pragma unroll
    for (int p = 0; p < 4; p++) { m_[i][p] = -1e30f; l_[i][p] = 0.f; }

  for (int jt = 0; jt < 4; ++jt) {
    __syncthreads();
    {
      int r = t >> 2, c = (t & 3) * 16;
      const u16* src = kb_ + ((size_t)b * 256 + jt * 64 + r) * ks + h * 64 + c;
      *(u16x8*)&Ks[r][c] = *(const u16x8*)src;
      *(u16x8*)&Ks[r][c + 8] = *(const u16x8*)(src + 8);
      int jj = t & 63;
      const u16* vsrc = vb + ((size_t)b * 256 + jt * 64 + jj) * vs + h * 64 + w * 16;
      u16x8 v0 = *(const u16x8*)vsrc;
      u16x8 v1 = *(const u16x8*)(vsrc + 8);
      #pragma unroll
      for (int d = 0; d < 8; d++) Vt[w * 16 + d][jj] = v0[d];
      #pragma unroll
      for (int d = 0; d < 8; d++) Vt[w * 16 + 8 + d][jj] = v1[d];
    }
    __syncthreads();

    B8 kf[2][4];
    #pragma unroll
    for (int kk = 0; kk < 2; kk++)
      #pragma unroll
      for (int n = 0; n < 4; n++)
        kf[kk][n].u = *(const u16x8*)&Ks[n * 16 + lr][kk * 32 + kg * 8];

    #pragma unroll
    for (int i = 0; i < 4; i++) {
      f32x4 s[4];
      #pragma unroll
      for (int n = 0; n < 4; n++) s[n] = f32x4{0.f, 0.f, 0.f, 0.f};
      #pragma unroll
      for (int kk = 0; kk < 2; kk++)
        #pragma unroll
        for (int n = 0; n < 4; n++)
          s[n] = __builtin_amdgcn_mfma_f32_16x16x32_bf16(qf[i][kk].b, kf[kk][n].b, s[n], 0, 0, 0);
      #pragma unroll
      for (int p = 0; p < 4; p++) {
        float pm = fmaxf(fmaxf(s[0][p], s[1][p]), fmaxf(s[2][p], s[3][p])) * 0.125f;
        #pragma unroll
        for (int mk = 1; mk < 16; mk <<= 1) pm = fmaxf(pm, __shfl_xor(pm, mk, 16));
        float mn = fmaxf(m_[i][p], pm);
        float scl = __expf(m_[i][p] - mn);
        m_[i][p] = mn;
        float rs = 0.f;
        #pragma unroll
        for (int n = 0; n < 4; n++) {
          float e = __expf(s[n][p] * 0.125f - mn);
          Pl[w][i * 16 + kg * 4 + p][n * 16 + lr] = f2bf(e);
          rs += e;
        }
        #pragma unroll
        for (int mk = 1; mk < 16; mk <<= 1) rs += __shfl_xor(rs, mk, 16);
        l_[i][p] = l_[i][p] * scl + rs;
        #pragma unroll
        for (int n2 = 0; n2 < 4; n2++) ao[i][n2][p] *= scl;
      }
    }

    B8 vf[2][4];
    #pragma unroll
    for (int kk = 0; kk < 2; kk++)
      #pragma unroll
      for (int n2 = 0; n2 < 4; n2++)
        vf[kk][n2].u = *(const u16x8*)&Vt[n2 * 16 + lr][kk * 32 + kg * 8];
    #pragma unroll
    for (int i = 0; i < 4; i++) {
      #pragma unroll
      for (int kk = 0; kk < 2; kk++) {
        B8 pa;
        pa.u = *(const u16x8*)&Pl[w][i * 16 + lr][kk * 32 + kg * 8];
        #pragma unroll
        for (int n2 = 0; n2 < 4; n2++)
          ao[i][n2] = __builtin_amdgcn_mfma_f32_16x16x32_bf16(pa.b, vf[kk][n2].b, ao[i][n2], 0, 0, 0);
      }
    }
  }

  #pragma unroll
  for (int i = 0; i < 4; i++) {
    #pragma unroll
    for (int p = 0; p < 4; p++) {
      const float inv = 1.0f / l_[i][p];
      const size_t row = qrow0 + i * 16 + kg * 4 + p;
      #pragma unroll
      for (int n2 = 0; n2 < 4; n2++)
        outp[row * 1024 + h * 64 + n2 * 16 + lr] = f2bf(ao[i][n2][p] * inv);
    }
  }
}

// ---------------- mean over T (coalesced) ----------------
__global__ __launch_bounds__(256) void mean2_kernel(const float* __restrict__ in,
                                                    float* __restrict__ out) {
  __shared__ float part[128];
  const int blk = blockIdx.x;
  const int b = blk >> 3, ch = blk & 7;
  const int t = threadIdx.x;
  const int col = ch * 128 + (t & 127);
  const int half = t >> 7;
  const float* p = in + (size_t)b * 262144 + (size_t)half * 131072 + col;
  float s = 0.f;
  for (int r = 0; r < 128; r++) s += p[(size_t)r * 1024];
  if (half) part[t & 127] = s;
  __syncthreads();
  if (!half) out[b * 1024 + col] = (s + part[t & 127]) * (1.0f / 256.0f);
}

// ---------------- router gate ----------------
__global__ __launch_bounds__(256) void gate_kernel(const float* __restrict__ x,
                                                   const float* __restrict__ ctx,
                                                   const float* __restrict__ gw,
                                                   const float* __restrict__ gb,
                                                   float* __restrict__ probs, int rowoff) {
  __shared__ float lg[8];
  const int tok = blockIdx.x;
  const int b = tok >> 8;
  const int t = threadIdx.x;
  const int e = t >> 5, sl = t & 31;
  const float* xr = x + (size_t)tok * 1024;
  const float* cr = ctx + (size_t)b * 1024;
  const float* wrow = gw + (size_t)e * 2048;
  float s = 0.f;
  for (int c = sl; c < 1024; c += 32) s += xr[c] * wrow[c] + cr[c] * wrow[1024 + c];
  #pragma unroll
  for (int o = 16; o > 0; o >>= 1) s += __shfl_down(s, o, 32);
  if (sl == 0) lg[e] = s + gb[e];
  __syncthreads();
  if (t == 0) {
    float mx = lg[0];
    #pragma unroll
    for (int i = 1; i < 8; i++) mx = fmaxf(mx, lg[i]);
    float ex[8], sum = 0.f;
    #pragma unroll
    for (int i = 0; i < 8; i++) { ex[i] = expf(lg[i] - mx); sum += ex[i]; }
    float inv = 1.0f / sum;
    #pragma unroll
    for (int i = 0; i < 8; i++) probs[(size_t)(rowoff + tok) * 8 + i] = ex[i] * inv;
  }
}

// ---------------- final: out = residual + moe_acc ----------------
__global__ __launch_bounds__(256) void final_add_kernel(const float* __restrict__ q3,
                                                        const float* __restrict__ img,
                                                        const float* __restrict__ moe,
                                                        float* __restrict__ out) {
  size_t i = (size_t)blockIdx.x * 256 + threadIdx.x;
  f32x4 m4 = *(const f32x4*)(moe + i * 4);
  f32x4 a4 = (i < 524288) ? *(const f32x4*)(q3 + i * 4)
                          : *(const f32x4*)(img + (i - 524288) * 4);
  f32x4 r;
  r[0] = a4[0] + m4[0]; r[1] = a4[1] + m4[1]; r[2] = a4[2] + m4[2]; r[3] = a4[3] + m4[3];
  *(f32x4*)(out + i * 4) = r;
}

// ================= launch =================
extern "C" void kernel_launch(void* const* d_in, const int* in_sizes, int n_in,
                              void* d_out, int out_size, void* d_ws, size_t ws_size,
                              hipStream_t stream) {
  const float* query_in = (const float*)d_in[0];
  const float* image_in = (const float*)d_in[1];
  const float* text_in  = (const float*)d_in[2];
  const float* sa_in_w  = (const float*)d_in[3];
  const float* sa_in_b  = (const float*)d_in[4];
  const float* sa_out_w = (const float*)d_in[5];
  const float* sa_out_b = (const float*)d_in[6];
  const float* ca_in_w  = (const float*)d_in[7];
  const float* ca_in_b  = (const float*)d_in[8];
  const float* ca_out_w = (const float*)d_in[9];
  const float* ca_out_b = (const float*)d_in[10];
  const float* img_gate_w = (const float*)d_in[11];
  const float* img_gate_b = (const float*)d_in[12];
  const float* txt_gate_w = (const float*)d_in[13];
  const float* txt_gate_b = (const float*)d_in[14];
  const float* lnq_g = (const float*)d_in[15];
  const float* lnq_b = (const float*)d_in[16];
  const float* lnc_g = (const float*)d_in[17];
  const float* lnc_b = (const float*)d_in[18];
  const float* lnf_g = (const float*)d_in[19];
  const float* lnf_b = (const float*)d_in[20];
  const float* ew1 = (const float*)d_in[21];
  const float* eb1 = (const float*)d_in[22];
  const float* ew2 = (const float*)d_in[23];
  const float* eb2 = (const float*)d_in[24];

  char* base = (char*)d_ws;
  size_t off = 0;
  auto alloc = [&](size_t bytes) -> char* {
    char* p = base + off;
    off += (bytes + 255) & ~(size_t)255;
    return p;
  };

  u16* wsa_in  = (u16*)alloc((size_t)3072 * 1024 * 2);
  u16* wsa_out = (u16*)alloc((size_t)1024 * 1024 * 2);
  u16* wca_in  = (u16*)alloc((size_t)3072 * 1024 * 2);
  u16* wca_out = (u16*)alloc((size_t)1024 * 1024 * 2);
  u16* w1T = (u16*)alloc((size_t)8 * 4096 * 1024 * 2);  // [E][F][H] bf16
  u16* w2T = (u16*)alloc((size_t)8 * 4096 * 1024 * 2);  // [E][H][F] bf16
  char* big = alloc((size_t)67108864);                  // 64MB: attn overlays, then h1 pair
  float* q3 = (float*)alloc((size_t)2048 * 1024 * 4);
  u16* xmoe = (u16*)alloc((size_t)4096 * 1024 * 2);
  float* moeac = (float*)alloc((size_t)4096 * 1024 * 4);
  float* probs = (float*)alloc((size_t)4096 * 8 * 4);
  float* ctx = (float*)alloc((size_t)2 * 8192 * 4);

  // big-region overlays (liveness-disjoint: attention phase, then MoE h1 pair)
  u16* qn      = (u16*)big;
  u16* qkv     = (u16*)(big + 4194304);                // [2048][3072]
  u16* attn_o  = (u16*)(big + 16777216);               // [2048][1024]
  float* q2    = (float*)(big + 20971520);             // [2048][1024] f32
  u16* cnorm   = (u16*)(big + 29360128);               // [2048][1024]
  u16* qca     = (u16*)(big + 33554432);               // [2048][1024]
  u16* kvca    = (u16*)(big + 37748736);               // [2048][2048]
  u16* h1p     = (u16*)big;                            // [2][4096][4096] bf16 = 64MB
  u16* img_bf  = xmoe + (size_t)2048 * 1024;           // image bf16 = MoE rows 2048+

  // ---- weight prep ----
  cast_kernel<<<3072, 256, 0, stream>>>(sa_in_w, wsa_in, 786432);
  cast_kernel<<<1024, 256, 0, stream>>>(sa_out_w, wsa_out, 262144);
  cast_kernel<<<3072, 256, 0, stream>>>(ca_in_w, wca_in, 786432);
  cast_kernel<<<1024, 256, 0, stream>>>(ca_out_w, wca_out, 262144);
  transpose_cast_kernel<<<dim3(128, 32, 8), dim3(32, 8), 0, stream>>>(ew1, w1T, 1024, 4096);
  transpose_cast_kernel<<<dim3(32, 128, 8), dim3(32, 8), 0, stream>>>(ew2, w2T, 4096, 1024);
  cast_kernel<<<2048, 256, 0, stream>>>(image_in, img_bf, 524288);

  // ---- self-attention ----
  ln_kernel<<<2048, 256, 0, stream>>>(query_in, lnq_g, lnq_b, qn);
  gemm_bt<0, 0, 0><<<dim3(24, 16), 256, 0, stream>>>(qn, wsa_in, sa_in_b, nullptr, qkv,
                                                     2048, 3072, 1024, 0, 1024, 0, 0, 0, 0);
  attn_mfma<<<128, 256, 0, stream>>>(qkv, 3072, qkv + 1024, 3072, qkv + 2048, 3072, attn_o);
  hipMemsetAsync(q2, 0, (size_t)2048 * 1024 * 4, stream);
  gemm_bt<1, 0, 0><<<dim3(8, 16, 2), 256, 0, stream>>>(attn_o, wsa_out, sa_out_b, query_in, q2,
                                                       2048, 1024, 1024, 0, 512, 0, 0, 0, 0);

  // ---- cross-attention ----
  ln_kernel<<<2048, 256, 0, stream>>>(q2, lnc_g, lnc_b, cnorm);
  gemm_bt<0, 0, 0><<<dim3(8, 16), 256, 0, stream>>>(cnorm, wca_in, ca_in_b, nullptr, qca,
                                                    2048, 1024, 1024, 0, 1024, 0, 0, 0, 0);
  gemm_bt<0, 0, 0><<<dim3(16, 16), 256, 0, stream>>>(img_bf, wca_in + (size_t)1024 * 1024,
                                                     ca_in_b + 1024, nullptr, kvca,
                                                     2048, 2048, 1024, 0, 1024, 0, 0, 0, 0);
  attn_mfma<<<128, 256, 0, stream>>>(qca, 1024, kvca, 2048, kvca + 1024, 2048, attn_o);
  hipMemsetAsync(q3, 0, (size_t)2048 * 1024 * 4, stream);
  gemm_bt<1, 0, 0><<<dim3(8, 16, 2), 256, 0, stream>>>(attn_o, wca_out, ca_out_b, q2, q3,
                                                       2048, 1024, 1024, 0, 512, 0, 0, 0, 0);

  // ---- gating ----
  mean2_kernel<<<64, 256, 0, stream>>>(image_in, ctx);
  mean2_kernel<<<64, 256, 0, stream>>>(text_in, ctx + 8192);
  gate_kernel<<<2048, 256, 0, stream>>>(q3, ctx, txt_gate_w, txt_gate_b, probs, 0);
  gate_kernel<<<2048, 256, 0, stream>>>(image_in, ctx + 8192, img_gate_w, img_gate_b, probs, 2048);

  // ---- MoE (rows 0..2047 = LN(q3), 2048..4095 = image bf16), expert pairs via z ----
  ln_kernel<<<2048, 256, 0, stream>>>(q3, lnf_g, lnf_b, xmoe);
  hipMemsetAsync(moeac, 0, (size_t)4096 * 1024 * 4, stream);
  for (int e0 = 0; e0 < 8; e0 += 2) {
    // w1: 2D A-resident XCD regions (R10-verified: FETCH 190->65MB)
    gemm_bt<2, 1, 2><<<dim3(32, 32, 2), 256, 0, stream>>>(
        xmoe, w1T + (size_t)e0 * 4194304, eb1 + (size_t)e0 * 4096, nullptr, h1p,
        4096, 4096, 1024, e0, 1024,
        /*saz*/ 0, /*sbz*/ 4194304, /*sbiasz*/ 4096, /*soutz*/ 16777216);
    // w2: 1D chunking, no split-K (P10 best)
    gemm_bt<3, 1, 0><<<dim3(8, 32, 2), 256, 0, stream>>>(
        h1p, w2T + (size_t)e0 * 4194304, eb2 + (size_t)e0 * 1024, probs, moeac,
        4096, 1024, 4096, e0, 4096,
        /*saz*/ 16777216, /*sbz*/ 4194304, /*sbiasz*/ 1024, /*soutz*/ 0);
  }

  // ---- final residual adds -> d_out ----
  final_add_kernel<<<4096, 256, 0, stream>>>(q3, image_in, moeac, (float*)d_out);
}

// Round 16
// 1119.082 us; speedup vs baseline: 1.4100x; 1.0106x over previous
//
#include <hip/hip_runtime.h>
#include <math.h>

// ---------------- types ----------------
typedef unsigned short u16;
typedef __bf16 bf16x8 __attribute__((ext_vector_type(8)));
typedef float  f32x4  __attribute__((ext_vector_type(4)));
typedef unsigned short u16x8 __attribute__((ext_vector_type(8)));
typedef unsigned short u16x4 __attribute__((ext_vector_type(4)));

union B8 { u16x8 u; bf16x8 b; };

__device__ __forceinline__ u16 f2bf(float x) {
  unsigned int u = __float_as_uint(x);
  unsigned int r = (u + 0x7fffu + ((u >> 16) & 1u)) >> 16;
  return (u16)r;
}
__device__ __forceinline__ float bf2f(u16 h) {
  return __uint_as_float(((unsigned int)h) << 16);
}

// async global->LDS, 16B per lane. lds ptr must be wave-uniform (HW adds lane*16).
__device__ __forceinline__ void gload16(const void* g, void* l) {
  __builtin_amdgcn_global_load_lds(
      (const __attribute__((address_space(1))) unsigned int*)g,
      (__attribute__((address_space(3))) unsigned int*)l, 16, 0, 0);
}

// ---------------- elementwise cast f32 -> bf16 ----------------
__global__ __launch_bounds__(256) void cast_kernel(const float* __restrict__ in,
                                                   u16* __restrict__ out, int n4) {
  int i = blockIdx.x * 256 + threadIdx.x;
  if (i >= n4) return;
  f32x4 v = *(const f32x4*)(in + (size_t)i * 4);
  u16x4 o;
  o[0] = f2bf(v[0]); o[1] = f2bf(v[1]); o[2] = f2bf(v[2]); o[3] = f2bf(v[3]);
  *(u16x4*)(out + (size_t)i * 4) = o;
}

// ---------------- transpose + cast: in [z][R][C] f32 -> out [z][C][R] bf16 ----------------
__global__ void transpose_cast_kernel(const float* __restrict__ in, u16* __restrict__ out,
                                      int R, int C) {
  __shared__ float tile[32][33];
  int z = blockIdx.z;
  int r0 = blockIdx.y * 32, c0 = blockIdx.x * 32;
  const float* ip = in + (size_t)z * R * C;
  u16* op = out + (size_t)z * R * C;
  int tx = threadIdx.x, ty = threadIdx.y;  // 32 x 8
  #pragma unroll
  for (int i = 0; i < 32; i += 8)
    tile[ty + i][tx] = ip[(size_t)(r0 + ty + i) * C + c0 + tx];
  __syncthreads();
  #pragma unroll
  for (int i = 0; i < 32; i += 8)
    op[(size_t)(c0 + ty + i) * R + r0 + tx] = f2bf(tile[tx][ty + i]);
}

// ---------------- LayerNorm (f32 in, bf16 out) ----------------
__global__ __launch_bounds__(256) void ln_kernel(const float* __restrict__ in,
                                                 const float* __restrict__ g,
                                                 const float* __restrict__ bt,
                                                 u16* __restrict__ out) {
  __shared__ float red[4];
  int row = blockIdx.x;
  int t = threadIdx.x;
  int lane = t & 63, wid = t >> 6;
  f32x4 x = *(const f32x4*)(in + (size_t)row * 1024 + t * 4);
  float s = x[0] + x[1] + x[2] + x[3];
  #pragma unroll
  for (int o = 32; o > 0; o >>= 1) s += __shfl_down(s, o, 64);
  if (lane == 0) red[wid] = s;
  __syncthreads();
  float mean = (red[0] + red[1] + red[2] + red[3]) * (1.0f / 1024.0f);
  __syncthreads();
  float d0 = x[0] - mean, d1 = x[1] - mean, d2 = x[2] - mean, d3 = x[3] - mean;
  float s2 = d0 * d0 + d1 * d1 + d2 * d2 + d3 * d3;
  #pragma unroll
  for (int o = 32; o > 0; o >>= 1) s2 += __shfl_down(s2, o, 64);
  if (lane == 0) red[wid] = s2;
  __syncthreads();
  float var = (red[0] + red[1] + red[2] + red[3]) * (1.0f / 1024.0f);
  float rstd = rsqrtf(var + 1e-5f);
  f32x4 gg = *(const f32x4*)(g + t * 4);
  f32x4 bb = *(const f32x4*)(bt + t * 4);
  u16x4 o;
  o[0] = f2bf(d0 * rstd * gg[0] + bb[0]);
  o[1] = f2bf(d1 * rstd * gg[1] + bb[1]);
  o[2] = f2bf(d2 * rstd * gg[2] + bb[2]);
  o[3] = f2bf(d3 * rstd * gg[3] + bb[3]);
  *(u16x4*)(out + (size_t)row * 1024 + t * 4) = o;
}

// fast GELU (tanh form): |err| vs erf-GELU <= ~1e-3 abs
__device__ __forceinline__ float gelu_f(float x) {
  float y = 0.79788456080286536f * (x + 0.044715f * x * x * x);
  return x - __fdividef(x, __expf(2.0f * y) + 1.0f);
}

// swizzle (BK=32 tiles, 4 granules of 16B per 64B row): slot = colg ^ (row bits 1..2)
// verified conflict-free (R6: SQ_LDS_BANK_CONFLICT = 0); both-sides consistent.
#define SRC_COL(t) ((((t) & 3) ^ (((t) >> 3) & 3)) * 8)

// ---------------- 128x128 GEMM: 4 waves, ahead-2 pipeline, 48KB LDS, 3 blocks/CU ----------
// Best-measured config (R11/R15: 1131us total). 3 bufs, counted vmcnt, A-resident chunks.
// CHUNK: 0 = 1D m-row chunks; 2 = 2D 4m x 2n A-resident regions.
// ZB=0: z = split-K chunk (bias/res on z==0). ZB=1: z = expert batch.
// MODE 0: bf16 = acc + bias (coalesced) | 1: f32 atomicAdd(acc+[z0](bias+res))
// MODE 2: bf16 = GELU(acc + bias)       | 3: f32 atomicAdd(prob*(acc+bias))
template <int MODE, int ZB, int CHUNK>
__global__ __launch_bounds__(256, 3) void gemm_bt(const u16* __restrict__ A,
                                                  const u16* __restrict__ B,
                                                  const float* __restrict__ bias,
                                                  const float* __restrict__ extra,
                                                  void* __restrict__ out,
                                                  int M, int N, int K, int expertBase,
                                                  int kChunk, size_t saz, size_t sbz,
                                                  int sbiasz, size_t soutz) {
  __shared__ u16 sm[24576];  // 3 bufs x (A[128][32] + B[128][32]) = 48KB
  const int tid = threadIdx.x;
  const int lane = tid & 63;
  const int wid = tid >> 6;
  const int wr = wid >> 1, wc = wid & 1;  // 2x2 waves, 64x64 each
  const int l15 = lane & 15;
  const int kg = lane >> 4;
  const int kgr8 = (kg ^ ((lane >> 1) & 3)) * 8;
  const int z = blockIdx.z;

  if (ZB) { A += (size_t)z * saz; B += (size_t)z * sbz; bias += z * sbiasz; }
  const int kOff = ZB ? 0 : z * kChunk;
  const bool z0 = ZB ? true : (z == 0);
  const int expert = expertBase + (ZB ? z : 0);

  const int gx = gridDim.x, gy = gridDim.y;
  const int bid = blockIdx.y * gx + blockIdx.x;
  const int xcd = bid & 7;
  const int idx = bid >> 3;
  int m0, n0;
  if constexpr (CHUNK == 0) {
    const int nwg = gx * gy;
    const int swz = xcd * (nwg >> 3) + idx;
    m0 = (swz / gx) * 128;
    n0 = (swz % gx) * 128;
  } else {
    const int hy = gy >> 2, hx = gx >> 1;
    const int cy = xcd >> 1, cx = xcd & 1;
    m0 = (cy * hy + idx % hy) * 128;   // m fastest: A region L2-resident
    n0 = (cx * hx + idx / hy) * 128;
  }

  f32x4 acc[4][4];
  #pragma unroll
  for (int i = 0; i < 4; i++)
    #pragma unroll
    for (int j = 0; j < 4; j++) acc[i][j] = f32x4{0.f, 0.f, 0.f, 0.f};

  const int sc = SRC_COL(tid);
  const u16* ga = A + (size_t)(m0 + (tid >> 2)) * K + sc + kOff;
  const u16* gb = B + (size_t)(n0 + (tid >> 2)) * K + sc + kOff;
  const size_t rowskip = (size_t)64 * K;

#define STG(b, kt)                                                  \
  do {                                                              \
    u16* d = sm + (b) * 8192 + wid * 512;                           \
    gload16(ga + (kt), d);                                          \
    gload16(ga + rowskip + (kt), d + 2048);                         \
    gload16(gb + (kt), d + 4096);                                   \
    gload16(gb + rowskip + (kt), d + 6144);                         \
  } while (0)

  const int NT = kChunk >> 5;
  STG(0, 0); STG(1, 32);
  int buf = 0;
  for (int t = 0; t < NT; ++t) {
    if (t + 1 < NT) asm volatile("s_waitcnt vmcnt(4)" ::: "memory");
    else            asm volatile("s_waitcnt vmcnt(0)" ::: "memory");
    __builtin_amdgcn_s_barrier();
    if (t + 2 < NT) {
      int nb = buf + 2; if (nb >= 3) nb -= 3;
      STG(nb, (t + 2) * 32);
    }
    __builtin_amdgcn_sched_barrier(0);
    __builtin_amdgcn_s_setprio(1);
    const u16* base = sm + buf * 8192;
    B8 af[4], bfr[4];
    #pragma unroll
    for (int i = 0; i < 4; i++) {
      af[i].u  = *(const u16x8*)(base + (wr * 64 + l15 + i * 16) * 32 + kgr8);
      bfr[i].u = *(const u16x8*)(base + 4096 + (wc * 64 + l15 + i * 16) * 32 + kgr8);
    }
    #pragma unroll
    for (int i = 0; i < 4; i++)
      #pragma unroll
      for (int j = 0; j < 4; j++)
        acc[i][j] = __builtin_amdgcn_mfma_f32_16x16x32_bf16(af[i].b, bfr[j].b, acc[i][j], 0, 0, 0);
    __builtin_amdgcn_s_setprio(0);
    if (++buf >= 3) buf = 0;
  }
#undef STG

  const int orow0 = m0 + wr * 64 + (lane >> 4) * 4;
  const int ocol0 = n0 + wc * 64 + l15;

  if constexpr (MODE == 0 || MODE == 2) {
    u16* outp = (u16*)out + (ZB ? (size_t)z * soutz : 0);
    __builtin_amdgcn_s_barrier();  // all sm reads done
    u16* rp = sm + wid * 1152;     // [16][72]
    const int mrow0 = m0 + wr * 64;
    const int cbase = n0 + wc * 64;
    #pragma unroll
    for (int i = 0; i < 4; i++) {
      #pragma unroll
      for (int j = 0; j < 4; j++) {
        const float bb = bias[cbase + j * 16 + l15];
        #pragma unroll
        for (int p = 0; p < 4; p++) {
          float vb = acc[i][j][p] + bb;
          if constexpr (MODE == 2) vb = gelu_f(vb);
          rp[((lane >> 4) * 4 + p) * 72 + j * 16 + l15] = f2bf(vb);
        }
      }
      asm volatile("s_waitcnt lgkmcnt(0)" ::: "memory");
      #pragma unroll
      for (int rr = 0; rr < 4; rr++) {
        const int r16 = rr * 4 + (lane >> 4);
        u16x4 v4 = *(const u16x4*)&rp[r16 * 72 + l15 * 4];
        *(u16x4*)(outp + (size_t)(mrow0 + i * 16 + r16) * N + cbase + l15 * 4) = v4;
      }
      asm volatile("s_waitcnt lgkmcnt(0)" ::: "memory");
    }
  } else {
    float* outp = (float*)out + (ZB ? (size_t)z * soutz : 0);
    #pragma unroll
    for (int i = 0; i < 4; i++) {
      float pr_[4];
      if constexpr (MODE == 3) {
        #pragma unroll
        for (int p = 0; p < 4; p++)
          pr_[p] = extra[(size_t)(orow0 + i * 16 + p) * 8 + expert];
      }
      #pragma unroll
      for (int j = 0; j < 4; j++) {
        const int gcol = ocol0 + j * 16;
        const float bb = bias[gcol];
        #pragma unroll
        for (int p = 0; p < 4; p++) {
          const int grow = orow0 + i * 16 + p;
          const size_t off = (size_t)grow * N + gcol;
          if constexpr (MODE == 1) {
            atomicAdd(&outp[off], acc[i][j][p] + (z0 ? bb + extra[off] : 0.f));
          } else {
            atomicAdd(&outp[off], pr_[p] * (acc[i][j][p] + bb));
          }
        }
      }
    }
  }
}

// ---------------- 256x256 8-phase GEMM (MoE w1): 8 waves, 4-slot K-ring, 128KB LDS -------
// Faithful port of the m201 fine-interleave: per K-step (BK=32) two phases, each
// {ds_read frags || stage one half of step s+3 -> s_barrier -> lgkmcnt(0) ->
//  setprio(1) 16 MFMA setprio(0) -> s_barrier}; step-boundary counted vmcnt(8).
// Ring safety: slot (s+3)%4's readers finished before end-of-step-(s-1) barrier.
// z = expert batch. Out: bf16 = GELU(acc + bias), coalesced.
__global__ __launch_bounds__(512, 2) void gemm8p(const u16* __restrict__ A,
                                                 const u16* __restrict__ B,
                                                 const float* __restrict__ bias,
                                                 u16* __restrict__ out,
                                                 int N, int K,
                                                 size_t sbz, int sbiasz, size_t soutz) {
  __shared__ u16 sm[65536];  // A: 4 slots x [256][32] = 64KB at 0; B same at +32768 u16
  const int tid = threadIdx.x;
  const int lane = tid & 63;
  const int wid = tid >> 6;        // 0..7
  const int wr = wid >> 2;         // 0..1  (m-half: 128 rows)
  const int wc = wid & 3;          // 0..3  (n-quarter: 64 cols)
  const int l15 = lane & 15;
  const int kg = lane >> 4;
  const int kgr8 = (kg ^ ((lane >> 1) & 3)) * 8;
  const int z = blockIdx.z;
  B += (size_t)z * sbz; bias += z * sbiasz;
  u16* outp = out + (size_t)z * soutz;

  // 2D A-resident XCD regions: gy=16 m-tiles, gx=16 n-tiles (256^2 tiles)
  const int gx = gridDim.x, gy = gridDim.y;
  const int bid = blockIdx.y * gx + blockIdx.x;
  const int xcd = bid & 7;
  const int idx = bid >> 3;
  const int hy = gy >> 2, hx = gx >> 1;
  const int cy = xcd >> 1, cx = xcd & 1;
  const int m0 = (cy * hy + idx % hy) * 256;
  const int n0 = (cx * hx + idx / hy) * 256;

  f32x4 acc[8][4];
  #pragma unroll
  for (int i = 0; i < 8; i++)
    #pragma unroll
    for (int j = 0; j < 4; j++) acc[i][j] = f32x4{0.f, 0.f, 0.f, 0.f};

  const int sc = SRC_COL(tid);
  // batch 0 = rows 0..127 of the 256-row tile, batch 1 = rows 128..255
  const u16* gaA0 = A + (size_t)(m0 + (tid >> 2)) * K + sc;
  const u16* gaA1 = A + (size_t)(m0 + 128 + (tid >> 2)) * K + sc;
  const u16* gbB0 = B + (size_t)(n0 + (tid >> 2)) * K + sc;
  const u16* gbB1 = B + (size_t)(n0 + 128 + (tid >> 2)) * K + sc;

#define STG_A(sp)                                                   \
  do {                                                              \
    u16* d = sm + ((sp) & 3) * 8192 + wid * 512;                    \
    gload16(gaA0 + (size_t)(sp) * 32, d);                           \
    gload16(gaA1 + (size_t)(sp) * 32, d + 4096);                    \
  } while (0)
#define STG_B(sp)                                                   \
  do {                                                              \
    u16* d = sm + 32768 + ((sp) & 3) * 8192 + wid * 512;            \
    gload16(gbB0 + (size_t)(sp) * 32, d);                           \
    gload16(gbB1 + (size_t)(sp) * 32, d + 4096);                    \
  } while (0)

  const int NT = K >> 5;  // K=1024 -> 32 steps
  STG_A(0); STG_B(0); STG_A(1); STG_B(1); STG_A(2); STG_B(2);
  asm volatile("s_waitcnt vmcnt(8)" ::: "memory");  // step 0 landed; 1,2 in flight
  __builtin_amdgcn_s_barrier();

  for (int s = 0; s < NT; ++s) {
    const u16* bA = sm + (s & 3) * 8192;
    const u16* bB = sm + 32768 + (s & 3) * 8192;
    // ---------- phase A: B frags + A[0..3]; stage A-half of step s+3 ----------
    B8 bfr[4], af[4];
    #pragma unroll
    for (int j = 0; j < 4; j++)
      bfr[j].u = *(const u16x8*)(bB + (wc * 64 + j * 16 + l15) * 32 + kgr8);
    #pragma unroll
    for (int i = 0; i < 4; i++)
      af[i].u = *(const u16x8*)(bA + (wr * 128 + i * 16 + l15) * 32 + kgr8);
    if (s + 3 < NT) STG_A(s + 3);
    __builtin_amdgcn_s_barrier();
    asm volatile("s_waitcnt lgkmcnt(0)" ::: "memory");
    __builtin_amdgcn_sched_barrier(0);
    __builtin_amdgcn_s_setprio(1);
    #pragma unroll
    for (int i = 0; i < 4; i++)
      #pragma unroll
      for (int j = 0; j < 4; j++)
        acc[i][j] = __builtin_amdgcn_mfma_f32_16x16x32_bf16(af[i].b, bfr[j].b, acc[i][j], 0, 0, 0);
    __builtin_amdgcn_s_setprio(0);
    __builtin_amdgcn_s_barrier();
    // ---------- phase B: A[4..7]; stage B-half of step s+3 ----------
    B8 af2[4];
    #pragma unroll
    for (int i = 0; i < 4; i++)
      af2[i].u = *(const u16x8*)(bA + (wr * 128 + (i + 4) * 16 + l15) * 32 + kgr8);
    if (s + 3 < NT) STG_B(s + 3);
    __builtin_amdgcn_s_barrier();
    asm volatile("s_waitcnt lgkmcnt(0)" ::: "memory");
    __builtin_amdgcn_sched_barrier(0);
    __builtin_amdgcn_s_setprio(1);
    #pragma unroll
    for (int i = 0; i < 4; i++)
      #pragma unroll
      for (int j = 0; j < 4; j++)
        acc[i + 4][j] = __builtin_amdgcn_mfma_f32_16x16x32_bf16(af2[i].b, bfr[j].b, acc[i + 4][j], 0, 0, 0);
    __builtin_amdgcn_s_setprio(0);
    // ---------- step boundary: step s+1 must be resident; keep 2 steps in flight ----------
    if (s + 3 < NT)      asm volatile("s_waitcnt vmcnt(8)" ::: "memory");
    else if (s + 2 < NT) asm volatile("s_waitcnt vmcnt(4)" ::: "memory");
    else                 asm volatile("s_waitcnt vmcnt(0)" ::: "memory");
    __builtin_amdgcn_s_barrier();
  }
#undef STG_A
#undef STG_B

  // epilogue: GELU + LDS repack -> coalesced 8B stores (R12-verified pattern)
  __builtin_amdgcn_s_barrier();
  u16* rp = sm + wid * 1152;  // [16][72] per wave
  const int mrow0 = m0 + wr * 128;
  const int cbase = n0 + wc * 64;
  #pragma unroll
  for (int i = 0; i < 8; i++) {
    #pragma unroll
    for (int j = 0; j < 4; j++) {
      const float bb = bias[cbase + j * 16 + l15];
      #pragma unroll
      for (int p = 0; p < 4; p++) {
        float vb = gelu_f(acc[i][j][p] + bb);
        rp[((lane >> 4) * 4 + p) * 72 + j * 16 + l15] = f2bf(vb);
      }
    }
    asm volatile("s_waitcnt lgkmcnt(0)" ::: "memory");
    #pragma unroll
    for (int rr = 0; rr < 4; rr++) {
      const int r16 = rr * 4 + (lane >> 4);
      u16x4 v4 = *(const u16x4*)&rp[r16 * 72 + l15 * 4];
      *(u16x4*)(outp + (size_t)(mrow0 + i * 16 + r16) * N + cbase + l15 * 4) = v4;
    }
    asm volatile("s_waitcnt lgkmcnt(0)" ::: "memory");
  }
}

// ---------------- MFMA flash attention: block=(b,head), 4 waves x 64 q-rows ----------------
__global__ __launch_bounds__(256) void attn_mfma(const u16* __restrict__ qb, int qs,
                                                 const u16* __restrict__ kb_, int ks,
                                                 const u16* __restrict__ vb, int vs,
                                                 u16* __restrict__ outp) {
  __shared__ u16 Ks[64][72];
  __shared__ u16 Vt[64][72];
  __shared__ u16 Pl[4][64][72];
  const int t = threadIdx.x;
  const int lane = t & 63;
  const int w = t >> 6;
  const int b = blockIdx.x >> 4;
  const int h = blockIdx.x & 15;
  const int lr = lane & 15;
  const int kg = lane >> 4;
  const size_t qrow0 = (size_t)b * 256 + w * 64;

  B8 qf[4][2];
  #pragma unroll
  for (int i = 0; i < 4; i++)
    #pragma unroll
    for (int kk = 0; kk < 2; kk++)
      qf[i][kk].u = *(const u16x8*)(qb + (qrow0 + i * 16 + lr) * qs + h * 64 + kk * 32 + kg * 8);

  f32x4 ao[4][4];
  float m_[4][4], l_[4][4];
  #pragma unroll
  for (int i = 0; i < 4; i++)
    #pragma unroll
    for (int n = 0; n < 4; n++) ao[i][n] = f32x4{0.f, 0.f, 0.f, 0.f};
  #pragma unroll
  for (int i = 0; i < 4; i++)
    #pragma unroll
    for (int p = 0; p < 4; p++) { m_[i][p] = -1e30f; l_[i][p] = 0.f; }

  for (int jt = 0; jt < 4; ++jt) {
    __syncthreads();
    {
      int r = t >> 2, c = (t & 3) * 16;
      const u16* src = kb_ + ((size_t)b * 256 + jt * 64 + r) * ks + h * 64 + c;
      *(u16x8*)&Ks[r][c] = *(const u16x8*)src;
      *(u16x8*)&Ks[r][c + 8] = *(const u16x8*)(src + 8);
      int jj = t & 63;
      const u16* vsrc = vb + ((size_t)b * 256 + jt * 64 + jj) * vs + h * 64 + w * 16;
      u16x8 v0 = *(const u16x8*)vsrc;
      u16x8 v1 = *(const u16x8*)(vsrc + 8);
      #pragma unroll
      for (int d = 0; d < 8; d++) Vt[w * 16 + d][jj] = v0[d];
      #pragma unroll
      for (int d = 0; d < 8; d++) Vt[w * 16 + 8 + d][jj] = v1[d];
    }
    __syncthreads();

    B8 kf[2][4];
    #pragma unroll
    for (int kk = 0; kk < 2; kk++)
      #pragma unroll
      for (int n = 0; n < 4; n++)
        kf[kk][n].u = *(const u16x8*)&Ks[n * 16 + lr][kk * 32 + kg * 8];

    #pragma unroll
    for (int i = 0; i < 4; i++) {
      f32x4 s[4];
      #pragma unroll
      for (int n = 0; n < 4; n++) s[n] = f32x4{0.f, 0.f, 0.f, 0.f};
      #pragma unroll
      for (int kk = 0; kk < 2; kk++)
        #pragma unroll
        for (int n = 0; n < 4; n++)
          s[n] = __builtin_amdgcn_mfma_f32_16x16x32_bf16(qf[i][kk].b, kf[kk][n].b, s[n], 0, 0, 0);
      #pragma unroll
      for (int p = 0; p < 4; p++) {
        float pm = fmaxf(fmaxf(s[0][p], s[1][p]), fmaxf(s[2][p], s[3][p])) * 0.125f;
        #pragma unroll
        for (int mk = 1; mk < 16; mk <<= 1) pm = fmaxf(pm, __shfl_xor(pm, mk, 16));
        float mn = fmaxf(m_[i][p], pm);
        float scl = __expf(m_[i][p] - mn);
        m_[i][p] = mn;
        float rs = 0.f;
        #pragma unroll
        for (int n = 0; n < 4; n++) {
          float e = __expf(s[n][p] * 0.125f - mn);
          Pl[w][i * 16 + kg * 4 + p][n * 16 + lr] = f2bf(e);
          rs += e;
        }
        #pragma unroll
        for (int mk = 1; mk < 16; mk <<= 1) rs += __shfl_xor(rs, mk, 16);
        l_[i][p] = l_[i][p] * scl + rs;
        #pragma unroll
        for (int n2 = 0; n2 < 4; n2++) ao[i][n2][p] *= scl;
      }
    }

    B8 vf[2][4];
    #pragma unroll
    for (int kk = 0; kk < 2; kk++)
      #pragma unroll
      for (int n2 = 0; n2 < 4; n2++)
        vf[kk][n2].u = *(const u16x8*)&Vt[n2 * 16 + lr][kk * 32 + kg * 8];
    #pragma unroll
    for (int i = 0; i < 4; i++) {
      #pragma unroll
      for (int kk = 0; kk < 2; kk++) {
        B8 pa;
        pa.u = *(const u16x8*)&Pl[w][i * 16 + lr][kk * 32 + kg * 8];
        #pragma unroll
        for (int n2 = 0; n2 < 4; n2++)
          ao[i][n2] = __builtin_amdgcn_mfma_f32_16x16x32_bf16(pa.b, vf[kk][n2].b, ao[i][n2], 0, 0, 0);
      }
    }
  }

  #pragma unroll
  for (int i = 0; i < 4; i++) {
    #pragma unroll
    for (int p = 0; p < 4; p++) {
      const float inv = 1.0f / l_[i][p];
      const size_t row = qrow0 + i * 16 + kg * 4 + p;
      #pragma unroll
      for (int n2 = 0; n2 < 4; n2++)
        outp[row * 1024 + h * 64 + n2 * 16 + lr] = f2bf(ao[i][n2][p] * inv);
    }
  }
}

// ---------------- mean over T (coalesced) ----------------
__global__ __launch_bounds__(256) void mean2_kernel(const float* __restrict__ in,
                                                    float* __restrict__ out) {
  __shared__ float part[128];
  const int blk = blockIdx.x;
  const int b = blk >> 3, ch = blk & 7;
  const int t = threadIdx.x;
  const int col = ch * 128 + (t & 127);
  const int half = t >> 7;
  const float* p = in + (size_t)b * 262144 + (size_t)half * 131072 + col;
  float s = 0.f;
  for (int r = 0; r < 128; r++) s += p[(size_t)r * 1024];
  if (half) part[t & 127] = s;
  __syncthreads();
  if (!half) out[b * 1024 + col] = (s + part[t & 127]) * (1.0f / 256.0f);
}

// ---------------- router gate ----------------
__global__ __launch_bounds__(256) void gate_kernel(const float* __restrict__ x,
                                                   const float* __restrict__ ctx,
                                                   const float* __restrict__ gw,
                                                   const float* __restrict__ gb,
                                                   float* __restrict__ probs, int rowoff) {
  __shared__ float lg[8];
  const int tok = blockIdx.x;
  const int b = tok >> 8;
  const int t = threadIdx.x;
  const int e = t >> 5, sl = t & 31;
  const float* xr = x + (size_t)tok * 1024;
  const float* cr = ctx + (size_t)b * 1024;
  const float* wrow = gw + (size_t)e * 2048;
  float s = 0.f;
  for (int c = sl; c < 1024; c += 32) s += xr[c] * wrow[c] + cr[c] * wrow[1024 + c];
  #pragma unroll
  for (int o = 16; o > 0; o >>= 1) s += __shfl_down(s, o, 32);
  if (sl == 0) lg[e] = s + gb[e];
  __syncthreads();
  if (t == 0) {
    float mx = lg[0];
    #pragma unroll
    for (int i = 1; i < 8; i++) mx = fmaxf(mx, lg[i]);
    float ex[8], sum = 0.f;
    #pragma unroll
    for (int i = 0; i < 8; i++) { ex[i] = expf(lg[i] - mx); sum += ex[i]; }
    float inv = 1.0f / sum;
    #pragma unroll
    for (int i = 0; i < 8; i++) probs[(size_t)(rowoff + tok) * 8 + i] = ex[i] * inv;
  }
}

// ---------------- final: out = residual + moe_acc ----------------
__global__ __launch_bounds__(256) void final_add_kernel(const float* __restrict__ q3,
                                                        const float* __restrict__ img,
                                                        const float* __restrict__ moe,
                                                        float* __restrict__ out) {
  size_t i = (size_t)blockIdx.x * 256 + threadIdx.x;
  f32x4 m4 = *(const f32x4*)(moe + i * 4);
  f32x4 a4 = (i < 524288) ? *(const f32x4*)(q3 + i * 4)
                          : *(const f32x4*)(img + (i - 524288) * 4);
  f32x4 r;
  r[0] = a4[0] + m4[0]; r[1] = a4[1] + m4[1]; r[2] = a4[2] + m4[2]; r[3] = a4[3] + m4[3];
  *(f32x4*)(out + i * 4) = r;
}

// ================= launch =================
extern "C" void kernel_launch(void* const* d_in, const int* in_sizes, int n_in,
                              void* d_out, int out_size, void* d_ws, size_t ws_size,
                              hipStream_t stream) {
  const float* query_in = (const float*)d_in[0];
  const float* image_in = (const float*)d_in[1];
  const float* text_in  = (const float*)d_in[2];
  const float* sa_in_w  = (const float*)d_in[3];
  const float* sa_in_b  = (const float*)d_in[4];
  const float* sa_out_w = (const float*)d_in[5];
  const float* sa_out_b = (const float*)d_in[6];
  const float* ca_in_w  = (const float*)d_in[7];
  const float* ca_in_b  = (const float*)d_in[8];
  const float* ca_out_w = (const float*)d_in[9];
  const float* ca_out_b = (const float*)d_in[10];
  const float* img_gate_w = (const float*)d_in[11];
  const float* img_gate_b = (const float*)d_in[12];
  const float* txt_gate_w = (const float*)d_in[13];
  const float* txt_gate_b = (const float*)d_in[14];
  const float* lnq_g = (const float*)d_in[15];
  const float* lnq_b = (const float*)d_in[16];
  const float* lnc_g = (const float*)d_in[17];
  const float* lnc_b = (const float*)d_in[18];
  const float* lnf_g = (const float*)d_in[19];
  const float* lnf_b = (const float*)d_in[20];
  const float* ew1 = (const float*)d_in[21];
  const float* eb1 = (const float*)d_in[22];
  const float* ew2 = (const float*)d_in[23];
  const float* eb2 = (const float*)d_in[24];

  char* base = (char*)d_ws;
  size_t off = 0;
  auto alloc = [&](size_t bytes) -> char* {
    char* p = base + off;
    off += (bytes + 255) & ~(size_t)255;
    return p;
  };

  u16* wsa_in  = (u16*)alloc((size_t)3072 * 1024 * 2);
  u16* wsa_out = (u16*)alloc((size_t)1024 * 1024 * 2);
  u16* wca_in  = (u16*)alloc((size_t)3072 * 1024 * 2);
  u16* wca_out = (u16*)alloc((size_t)1024 * 1024 * 2);
  u16* w1T = (u16*)alloc((size_t)8 * 4096 * 1024 * 2);  // [E][F][H] bf16
  u16* w2T = (u16*)alloc((size_t)8 * 4096 * 1024 * 2);  // [E][H][F] bf16
  char* big = alloc((size_t)67108864);                  // 64MB: attn overlays, then h1 pair
  float* q3 = (float*)alloc((size_t)2048 * 1024 * 4);
  u16* xmoe = (u16*)alloc((size_t)4096 * 1024 * 2);
  float* moeac = (float*)alloc((size_t)4096 * 1024 * 4);
  float* probs = (float*)alloc((size_t)4096 * 8 * 4);
  float* ctx = (float*)alloc((size_t)2 * 8192 * 4);

  // big-region overlays (liveness-disjoint: attention phase, then MoE h1 pair)
  u16* qn      = (u16*)big;
  u16* qkv     = (u16*)(big + 4194304);                // [2048][3072]
  u16* attn_o  = (u16*)(big + 16777216);               // [2048][1024]
  float* q2    = (float*)(big + 20971520);             // [2048][1024] f32
  u16* cnorm   = (u16*)(big + 29360128);               // [2048][1024]
  u16* qca     = (u16*)(big + 33554432);               // [2048][1024]
  u16* kvca    = (u16*)(big + 37748736);               // [2048][2048]
  u16* h1p     = (u16*)big;                            // [2][4096][4096] bf16 = 64MB
  u16* img_bf  = xmoe + (size_t)2048 * 1024;           // image bf16 = MoE rows 2048+

  // ---- weight prep ----
  cast_kernel<<<3072, 256, 0, stream>>>(sa_in_w, wsa_in, 786432);
  cast_kernel<<<1024, 256, 0, stream>>>(sa_out_w, wsa_out, 262144);
  cast_kernel<<<3072, 256, 0, stream>>>(ca_in_w, wca_in, 786432);
  cast_kernel<<<1024, 256, 0, stream>>>(ca_out_w, wca_out, 262144);
  transpose_cast_kernel<<<dim3(128, 32, 8), dim3(32, 8), 0, stream>>>(ew1, w1T, 1024, 4096);
  transpose_cast_kernel<<<dim3(32, 128, 8), dim3(32, 8), 0, stream>>>(ew2, w2T, 4096, 1024);
  cast_kernel<<<2048, 256, 0, stream>>>(image_in, img_bf, 524288);

  // ---- self-attention ----
  ln_kernel<<<2048, 256, 0, stream>>>(query_in, lnq_g, lnq_b, qn);
  gemm_bt<0, 0, 0><<<dim3(24, 16), 256, 0, stream>>>(qn, wsa_in, sa_in_b, nullptr, qkv,
                                                     2048, 3072, 1024, 0, 1024, 0, 0, 0, 0);
  attn_mfma<<<128, 256, 0, stream>>>(qkv, 3072, qkv + 1024, 3072, qkv + 2048, 3072, attn_o);
  hipMemsetAsync(q2, 0, (size_t)2048 * 1024 * 4, stream);
  gemm_bt<1, 0, 0><<<dim3(8, 16, 2), 256, 0, stream>>>(attn_o, wsa_out, sa_out_b, query_in, q2,
                                                       2048, 1024, 1024, 0, 512, 0, 0, 0, 0);

  // ---- cross-attention ----
  ln_kernel<<<2048, 256, 0, stream>>>(q2, lnc_g, lnc_b, cnorm);
  gemm_bt<0, 0, 0><<<dim3(8, 16), 256, 0, stream>>>(cnorm, wca_in, ca_in_b, nullptr, qca,
                                                    2048, 1024, 1024, 0, 1024, 0, 0, 0, 0);
  gemm_bt<0, 0, 0><<<dim3(16, 16), 256, 0, stream>>>(img_bf, wca_in + (size_t)1024 * 1024,
                                                     ca_in_b + 1024, nullptr, kvca,
                                                     2048, 2048, 1024, 0, 1024, 0, 0, 0, 0);
  attn_mfma<<<128, 256, 0, stream>>>(qca, 1024, kvca, 2048, kvca + 1024, 2048, attn_o);
  hipMemsetAsync(q3, 0, (size_t)2048 * 1024 * 4, stream);
  gemm_bt<1, 0, 0><<<dim3(8, 16, 2), 256, 0, stream>>>(attn_o, wca_out, ca_out_b, q2, q3,
                                                       2048, 1024, 1024, 0, 512, 0, 0, 0, 0);

  // ---- gating ----
  mean2_kernel<<<64, 256, 0, stream>>>(image_in, ctx);
  mean2_kernel<<<64, 256, 0, stream>>>(text_in, ctx + 8192);
  gate_kernel<<<2048, 256, 0, stream>>>(q3, ctx, txt_gate_w, txt_gate_b, probs, 0);
  gate_kernel<<<2048, 256, 0, stream>>>(image_in, ctx + 8192, img_gate_w, img_gate_b, probs, 2048);

  // ---- MoE (rows 0..2047 = LN(q3), 2048..4095 = image bf16), expert pairs via z ----
  ln_kernel<<<2048, 256, 0, stream>>>(q3, lnf_g, lnf_b, xmoe);
  hipMemsetAsync(moeac, 0, (size_t)4096 * 1024 * 4, stream);
  for (int e0 = 0; e0 < 8; e0 += 2) {
    // w1: 8-phase 256^2 kernel, grid 512 blocks (2 experts), A-resident XCD regions
    gemm8p<<<dim3(16, 16, 2), 512, 0, stream>>>(
        xmoe, w1T + (size_t)e0 * 4194304, eb1 + (size_t)e0 * 4096, h1p,
        4096, 1024, /*sbz*/ 4194304, /*sbiasz*/ 4096, /*soutz*/ 16777216);
    // w2: R11-best 128^2 kernel, 1D chunking, no split-K
    gemm_bt<3, 1, 0><<<dim3(8, 32, 2), 256, 0, stream>>>(
        h1p, w2T + (size_t)e0 * 4194304, eb2 + (size_t)e0 * 1024, probs, moeac,
        4096, 1024, 4096, e0, 4096,
        /*saz*/ 16777216, /*sbz*/ 4194304, /*sbiasz*/ 1024, /*soutz*/ 0);
  }

  // ---- final residual adds -> d_out ----
  final_add_kernel<<<4096, 256, 0, stream>>>(q3, image_in, moeac, (float*)d_out);
}